// Round 1
// baseline (227.023 us; speedup 1.0000x reference)
//
#include <hip/hip_runtime.h>
#include <math.h>

#define BB 64
#define HH 30
#define WW 60
#define DD 64
#define NPIX 1800   // H*W

// pooled region counts: scale0 5x10=50 (6x6 px), scale1 3x6=18 (10x10), scale2 2x4=8 (15x15)
// Psum layout per batch: [0..50) s0, [50..68) s1, [68..76) s2; each region = 64 floats
#define NREG 76

// common-refinement bands
__constant__ int c_rowband[HH] = {0,0,0,0,0,0, 1,1,1,1, 2,2, 3,3,3, 4,4,4, 5,5, 6,6,6,6, 7,7,7,7,7,7};
__constant__ int c_colband[WW] = {0,0,0,0,0,0, 1,1,1,1, 2,2, 3,3,3, 4,4,4, 5,5, 6,6,6,6, 7,7,7,7,7,7,
                                  8,8,8,8,8,8, 9,9,9,9, 10,10, 11,11,11, 12,12,12, 13,13, 14,14,14,14, 15,15,15,15,15,15};
__constant__ int c_rowb_start[8]  = {0,6,10,12,15,18,20,24};
__constant__ int c_colb_start[16] = {0,6,10,12,15,18,20,24,30,36,40,42,45,48,50,54};

// ---------------- Kernel A: k-projection + region-sum pooling ----------------
// grid = BB*HH, block = 256 (4 waves; wave g handles pixels [g*15, g*15+15))
__global__ __launch_bounds__(256) void ka_kproj_pool(
    const float* __restrict__ x, const float* __restrict__ qk_w,
    const float* __restrict__ qk_b, float* __restrict__ psum)
{
    __shared__ float wkT[64 * 64];        // [d][j] = qk_w[64+j][d]
    __shared__ float pools[4][20 * 64];   // per-wave: 10 s0-cols, 6 s1-cols, 4 s2-cols

    const int b = blockIdx.x / HH;
    const int h = blockIdx.x % HH;
    const int t = threadIdx.x;
    const int j = t & 63;
    const int g = t >> 6;

    // load Wk transposed into LDS (reads stride-64 from global but L2-hot; LDS writes conflict-free)
    for (int idx = t; idx < 4096; idx += 256) {
        int d = idx >> 6, jj = idx & 63;
        wkT[d * 64 + jj] = qk_w[(64 + jj) * 64 + d];
    }
    for (int idx = t; idx < 4 * 20 * 64; idx += 256) ((float*)pools)[idx] = 0.0f;
    __syncthreads();

    // pull my Wk column into registers
    float wreg[64];
#pragma unroll
    for (int d = 0; d < 64; ++d) wreg[d] = wkT[d * 64 + j];
    const float bkv = qk_b[64 + j];

    const float4* x4 = (const float4*)(x + (size_t)(b * NPIX + h * WW) * DD);
    float* mypool = &pools[g][0];

    for (int i = 0; i < 15; ++i) {
        const int p = g * 15 + i;
        float a0 = 0.f, a1 = 0.f, a2 = 0.f, a3 = 0.f;
#pragma unroll
        for (int d4 = 0; d4 < 16; ++d4) {
            float4 xv = x4[p * 16 + d4];   // wave-uniform address -> broadcast load
            a0 += xv.x * wreg[4 * d4 + 0];
            a1 += xv.y * wreg[4 * d4 + 1];
            a2 += xv.z * wreg[4 * d4 + 2];
            a3 += xv.w * wreg[4 * d4 + 3];
        }
        const float kval = bkv + ((a0 + a1) + (a2 + a3));
        // column-region accumulate (thread (g,j) exclusively owns pools[g][*][j])
        mypool[(p / 6) * 64 + j]        += kval;
        mypool[(10 + p / 10) * 64 + j]  += kval;
        mypool[(16 + p / 15) * 64 + j]  += kval;
    }
    __syncthreads();

    // reduce 4 wave-copies, scatter to global region sums
    const int r0row = (h / 6) * 10, r1row = (h / 10) * 6, r2row = (h / 15) * 4;
    for (int idx = t; idx < 20 * 64; idx += 256) {
        const int c = idx >> 6, jj = idx & 63;
        float s = pools[0][idx] + pools[1][idx] + pools[2][idx] + pools[3][idx];
        int r;
        if (c < 10)      r = r0row + c;
        else if (c < 16) r = 50 + r1row + (c - 10);
        else             r = 68 + r2row + (c - 16);
        atomicAdd(&psum[((size_t)b * NREG + r) * 64 + jj], s);
    }
}

// ---------------- Kernel B: per-cell combined vector -> G, c ----------------
// grid = BB, block = 256
__global__ __launch_bounds__(256) void kb_cellG(
    const float* __restrict__ qk_w, const float* __restrict__ qk_b,
    const float* __restrict__ score_w, const float* __restrict__ score_b,
    const float* __restrict__ psum, float* __restrict__ G, float* __restrict__ cc)
{
    __shared__ float M[128 * 64];   // 32 KB
    const int b = blockIdx.x;
    const int t = threadIdx.x;
    const float w0 = score_w[0] * (1.0f / 36.0f);
    const float w1 = score_w[1] * (1.0f / 100.0f);
    const float w2 = score_w[2] * (1.0f / 225.0f);
    const float scale = 0.125f;   // 64^-0.5
    const float* pb = psum + (size_t)b * NREG * 64;

    for (int idx = t; idx < 128 * 64; idx += 256) {
        const int cell = idx >> 6, jj = idx & 63;
        const int rb = cell >> 4, cb = cell & 15;
        const int h0 = c_rowb_start[rb], w0c = c_colb_start[cb];
        const int r0 = (h0 / 6) * 10 + w0c / 6;
        const int r1 = 50 + (h0 / 10) * 6 + w0c / 10;
        const int r2 = 68 + (h0 / 15) * 4 + w0c / 15;
        M[idx] = w0 * pb[r0 * 64 + jj] + w1 * pb[r1 * 64 + jj] + w2 * pb[r2 * 64 + jj];
    }
    __syncthreads();

    for (int idx = t; idx < 128 * 64; idx += 256) {
        const int cell = idx >> 6, d = idx & 63;
        float acc = 0.0f;
#pragma unroll 8
        for (int jj = 0; jj < 64; ++jj)
            acc += qk_w[jj * 64 + d] * M[cell * 64 + jj];   // M read is wave-broadcast
        G[(size_t)b * 8192 + idx] = acc * scale;
    }
    const float sb = score_b[0];
    if (t < 128) {
        float acc = 0.0f;
        for (int jj = 0; jj < 64; ++jj) acc += qk_b[jj] * M[t * 64 + jj];
        cc[b * 128 + t] = acc * scale + sb;
    }
}

// ---------------- Kernel C: per-pixel dot + gumbel-sigmoid mask ----------------
// grid = BB*HH, block = 256
__global__ __launch_bounds__(256) void kc_mask(
    const float* __restrict__ x, const float* __restrict__ G,
    const float* __restrict__ cc, const float* __restrict__ noise_x,
    const float* __restrict__ noise_r, float* __restrict__ out)
{
    __shared__ float Grow[16 * 64];
    __shared__ float crow[16];
    const int b = blockIdx.x / HH;
    const int h = blockIdx.x % HH;
    const int t = threadIdx.x;
    const int lane = t & 63;
    const int g = t >> 6;
    const int rb = c_rowband[h];

    for (int idx = t; idx < 1024; idx += 256)
        Grow[idx] = G[(size_t)b * 8192 + (size_t)rb * 1024 + idx];
    if (t < 16) crow[t] = cc[b * 128 + rb * 16 + t];
    __syncthreads();

    const float* xrow = x + (size_t)(b * NPIX + h * WW) * DD;
    const int pixbase = b * NPIX + h * WW;
    const float INV_T = 1.0f / (0.03f + 1e-8f);

    for (int i = 0; i < 15; ++i) {
        const int p = g * 15 + i;
        const int cb = c_colband[p];
        float v = xrow[p * 64 + lane] * Grow[cb * 64 + lane];
#pragma unroll
        for (int off = 32; off > 0; off >>= 1) v += __shfl_xor(v, off, 64);
        if (lane == 0) {
            const float attn = v + crow[cb];
            const float s  = 1.0f / (1.0f + expf(-attn));
            const float gx = logf(s + 1e-8f);
            const float gr = logf(1.0f - s + 1e-8f);
            const float ux = noise_x[pixbase + p];
            const float ur = noise_r[pixbase + p];
            const float nx = -logf(-logf(ux + 1e-8f) + 1e-8f);
            const float nr = -logf(-logf(ur + 1e-8f) + 1e-8f);
            const float A = (gx + nx) * INV_T;
            const float R = (gr + nr) * INV_T;
            out[pixbase + p] = 1.0f / (1.0f + expf(R - A));
        }
    }
}

extern "C" void kernel_launch(void* const* d_in, const int* in_sizes, int n_in,
                              void* d_out, int out_size, void* d_ws, size_t ws_size,
                              hipStream_t stream)
{
    const float* x       = (const float*)d_in[0];
    const float* qk_w    = (const float*)d_in[1];
    const float* qk_b    = (const float*)d_in[2];
    const float* score_w = (const float*)d_in[3];
    const float* score_b = (const float*)d_in[4];
    const float* noise_x = (const float*)d_in[5];
    const float* noise_r = (const float*)d_in[6];
    float* out = (float*)d_out;

    float* psum = (float*)d_ws;                    // 64*76*64 = 311296 floats
    float* G    = psum + (size_t)BB * NREG * 64;   // 64*128*64 = 524288 floats
    float* cc   = G + (size_t)BB * 128 * 64;       // 64*128    = 8192 floats

    hipMemsetAsync(d_ws, 0, (size_t)BB * NREG * 64 * sizeof(float), stream);
    ka_kproj_pool<<<BB * HH, 256, 0, stream>>>(x, qk_w, qk_b, psum);
    kb_cellG<<<BB, 256, 0, stream>>>(qk_w, qk_b, score_w, score_b, psum, G, cc);
    kc_mask<<<BB * HH, 256, 0, stream>>>(x, G, cc, noise_x, noise_r, out);
}

// Round 2
// 112.526 us; speedup vs baseline: 2.0175x; 2.0175x over previous
//
#include <hip/hip_runtime.h>
#include <math.h>

#define BB 64
#define HH 30
#define WW 60
#define DD 64
#define NPIX 1800
#define NREG 76   // 50 s0 (6x6) + 18 s1 (10x10) + 8 s2 (15x15)

// common-refinement bands: 8 row-bands x 16 col-bands
__constant__ int c_rowband[HH] = {0,0,0,0,0,0, 1,1,1,1, 2,2, 3,3,3, 4,4,4, 5,5, 6,6,6,6, 7,7,7,7,7,7};
__constant__ int c_colband[WW] = {0,0,0,0,0,0, 1,1,1,1, 2,2, 3,3,3, 4,4,4, 5,5, 6,6,6,6, 7,7,7,7,7,7,
                                  8,8,8,8,8,8, 9,9,9,9, 10,10, 11,11,11, 12,12,12, 13,13, 14,14,14,14, 15,15,15,15,15,15};
// colband -> scale-0 col (width 6) and scale-1 col (width 10)
__constant__ int c_s0col[16] = {0,1,1,2,2,3,3,4,5,6,6,7,7,8,8,9};
__constant__ int c_s1col[16] = {0,0,1,1,1,1,2,2,3,3,4,4,4,4,5,5};
// rowband -> scale-0 row, scale-1 row
__constant__ int c_s0row[8] = {0,1,1,2,2,3,3,4};
__constant__ int c_s1row[8] = {0,0,1,1,1,1,2,2};

// ---------------- Kernel A: pure pooling of x into per-region sums ----------------
// grid = BB*HH (one row per block), block = 256. Wave g owns pixels [15g,15g+15);
// colband boundaries align with 15-pixel quarters, so each wave has exactly 4
// colband register accumulators; they combine into 3 s0 + 2 s1 + 1 s2 atomics.
__global__ __launch_bounds__(256) void ka_pool(
    const float* __restrict__ x, float* __restrict__ psum)
{
    const int b = blockIdx.x / HH;
    const int h = blockIdx.x % HH;
    const int t = threadIdx.x;
    const int j = t & 63;
    const int g = t >> 6;

    const float* xrow = x + ((size_t)(b * NPIX + h * WW) + g * 15) * DD;
    float v[15];
#pragma unroll
    for (int i = 0; i < 15; ++i) v[i] = xrow[i * DD + j];

    float a0, a1, a2, a3;   // 4 colband sums (widths 6,4,2,3 for even waves; 3,2,4,6 for odd)
    if ((g & 1) == 0) {
        a0 = ((v[0]+v[1])+(v[2]+v[3]))+(v[4]+v[5]);
        a1 = (v[6]+v[7])+(v[8]+v[9]);
        a2 = v[10]+v[11];
        a3 = (v[12]+v[13])+v[14];
    } else {
        a0 = (v[0]+v[1])+v[2];
        a1 = v[3]+v[4];
        a2 = (v[5]+v[6])+(v[7]+v[8]);
        a3 = ((v[9]+v[10])+(v[11]+v[12]))+(v[13]+v[14]);
    }

    const float s0m = a1 + a2;           // middle s0 col of this wave
    const float s10 = a0 + a1;           // first s1 col
    const float s11 = a2 + a3;           // second s1 col
    const float s2  = s10 + s11;         // whole wave = one s2 col

    const int r0 = (h / 6) * 10;
    const int r1 = 50 + (h / 10) * 6;
    const int r2 = 68 + (h / 15) * 4;
    const int c0a = c_s0col[4*g], c0b = c_s0col[4*g+1], c0c = c_s0col[4*g+3];
    const int c1a = c_s1col[4*g], c1b = c_s1col[4*g+2];

    float* pb = psum + (size_t)b * NREG * 64 + j;
    atomicAdd(pb + (r0 + c0a) * 64, a0);
    atomicAdd(pb + (r0 + c0b) * 64, s0m);
    atomicAdd(pb + (r0 + c0c) * 64, a3);
    atomicAdd(pb + (r1 + c1a) * 64, s10);
    atomicAdd(pb + (r1 + c1b) * 64, s11);
    atomicAdd(pb + (r2 + g) * 64, s2);
}

// ---------------- Kernel B: per-cell G, c from region sums ----------------
// grid = BB*4 (quarter of the 128 cells per block), block = 256.
// M[cell] = Wk*xcomb[cell] + (w0+w1+w2)*bk,  xcomb = sum_s (w_s/n_s)*xsum_region
// G[cell] = scale*Wq^T*M[cell],  c[cell] = scale*bq.M[cell] + score_b
__global__ __launch_bounds__(256) void kb_cells(
    const float* __restrict__ qk_w, const float* __restrict__ qk_b,
    const float* __restrict__ score_w, const float* __restrict__ score_b,
    const float* __restrict__ psum, float* __restrict__ G, float* __restrict__ cc)
{
    __shared__ float R[NREG * 64];      // 19 KB region sums
    __shared__ float WQ[64 * 64];       // 16 KB, row-major [j][d]
    __shared__ float WKT[64 * 65];      // 16.25 KB padded transpose [d][j]
    __shared__ float XCOMB[32 * 64];    // 8 KB, this block's 32 cells
    __shared__ float M[32 * 64];        // 8 KB
    __shared__ float BQ[64];

    const int b = blockIdx.x >> 2;
    const int cell0 = (blockIdx.x & 3) * 32;
    const int t = threadIdx.x;
    const int lane = t & 63;
    const int g = t >> 6;

    for (int i = t; i < NREG * 64; i += 256) R[i] = psum[(size_t)b * NREG * 64 + i];
    for (int i = t; i < 4096; i += 256) {
        const int jj = i >> 6, d = i & 63;
        WQ[i] = qk_w[i];                              // coalesced
        WKT[d * 65 + jj] = qk_w[(64 + jj) * 64 + d];  // coalesced read, conflict-free write
    }
    if (t < 64) BQ[t] = qk_b[t];
    __syncthreads();

    const float w0 = score_w[0] * (1.0f / 36.0f);
    const float w1 = score_w[1] * (1.0f / 100.0f);
    const float w2 = score_w[2] * (1.0f / 225.0f);
    const float wsum = score_w[0] + score_w[1] + score_w[2];

    for (int i = t; i < 32 * 64; i += 256) {
        const int lcell = i >> 6, d = i & 63;
        const int cell = cell0 + lcell;
        const int rb = cell >> 4, cb = cell & 15;
        const int r0 = 10 * c_s0row[rb] + c_s0col[cb];
        const int r1 = 50 + 6 * c_s1row[rb] + c_s1col[cb];
        const int r2 = 68 + 4 * (rb >> 2) + (cb >> 2);
        XCOMB[i] = w0 * R[r0 * 64 + d] + w1 * R[r1 * 64 + d] + w2 * R[r2 * 64 + d];
    }
    __syncthreads();

    // M phase: lane j holds Wk row j in registers; xcomb broadcast from LDS
    {
        float wkreg[64];
#pragma unroll
        for (int d = 0; d < 64; ++d) wkreg[d] = WKT[d * 65 + lane];
        const float bkv = qk_b[64 + lane];
        for (int cidx = 0; cidx < 8; ++cidx) {
            const int lcell = g * 8 + cidx;
            const float4* xc = (const float4*)(XCOMB + lcell * 64);
            float acc = 0.f;
#pragma unroll
            for (int q = 0; q < 16; ++q) {
                const float4 m4 = xc[q];
                acc += m4.x * wkreg[4*q] + m4.y * wkreg[4*q+1]
                     + m4.z * wkreg[4*q+2] + m4.w * wkreg[4*q+3];
            }
            M[lcell * 64 + lane] = acc + wsum * bkv;
        }
    }
    __syncthreads();

    // G phase: lane d holds Wq column d in registers; M broadcast from LDS
    {
        float wqreg[64];
#pragma unroll
        for (int jj = 0; jj < 64; ++jj) wqreg[jj] = WQ[jj * 64 + lane];
        const float scl = 0.125f;   // 64^-0.5
        const float sb = score_b[0];
        const float4* bq4 = (const float4*)BQ;
        for (int cidx = 0; cidx < 8; ++cidx) {
            const int lcell = g * 8 + cidx;
            const float4* m4p = (const float4*)(M + lcell * 64);
            float acc = 0.f, cacc = 0.f;
#pragma unroll
            for (int q = 0; q < 16; ++q) {
                const float4 m4 = m4p[q];
                const float4 b4 = bq4[q];
                acc  += m4.x * wqreg[4*q] + m4.y * wqreg[4*q+1]
                      + m4.z * wqreg[4*q+2] + m4.w * wqreg[4*q+3];
                cacc += m4.x * b4.x + m4.y * b4.y + m4.z * b4.z + m4.w * b4.w;
            }
            const int cell = cell0 + lcell;
            G[(size_t)b * 8192 + cell * 64 + lane] = scl * acc;
            if (lane == 0) cc[b * 128 + cell] = scl * cacc + sb;
        }
    }
}

// ---------------- Kernel C: per-pixel dot + gumbel-sigmoid mask ----------------
// grid = BB*HH, block = 256. float4 loads: 16 lanes per pixel, 4 pixels per instr,
// 4-step shfl reduce within 16-lane groups; epilogue parallel over 60 threads.
__global__ __launch_bounds__(256) void kc_mask(
    const float* __restrict__ x, const float* __restrict__ G,
    const float* __restrict__ cc, const float* __restrict__ noise_x,
    const float* __restrict__ noise_r, float* __restrict__ out)
{
    __shared__ float Grow[1024];
    __shared__ float crow[16];
    __shared__ float attnv[64];
    __shared__ int cbt[64];

    const int b = blockIdx.x / HH;
    const int h = blockIdx.x % HH;
    const int t = threadIdx.x;
    const int lane = t & 63;
    const int g = t >> 6;
    const int rb = c_rowband[h];

    ((float4*)Grow)[t] = ((const float4*)(G + (size_t)b * 8192 + rb * 1024))[t];
    if (t < 16) crow[t] = cc[b * 128 + rb * 16 + t];
    if (t < 60) cbt[t] = c_colband[t];
    __syncthreads();

    const float4* x4 = (const float4*)(x + (size_t)(b * NPIX + h * WW) * DD);
    const int f = lane & 15;
    const int pg = lane >> 4;
#pragma unroll
    for (int i = 0; i < 4; ++i) {
        const int pl = i * 4 + pg;
        if (pl < 15) {
            const int p = g * 15 + pl;
            const int cb = cbt[p];
            const float4 xv = x4[p * 16 + f];
            const float4 gv = ((const float4*)Grow)[cb * 16 + f];
            float s = xv.x * gv.x + xv.y * gv.y + xv.z * gv.z + xv.w * gv.w;
            s += __shfl_xor(s, 1, 64);
            s += __shfl_xor(s, 2, 64);
            s += __shfl_xor(s, 4, 64);
            s += __shfl_xor(s, 8, 64);
            if (f == 0) attnv[p] = s + crow[cb];
        }
    }
    __syncthreads();

    if (t < 60) {
        const int pix = b * NPIX + h * WW + t;
        const float a = attnv[t];
        const float s  = 1.0f / (1.0f + expf(-a));
        const float gx = logf(s + 1e-8f);
        const float gr = logf(1.0f - s + 1e-8f);
        const float ux = noise_x[pix];
        const float ur = noise_r[pix];
        const float nx = -logf(-logf(ux + 1e-8f) + 1e-8f);
        const float nr = -logf(-logf(ur + 1e-8f) + 1e-8f);
        const float INV_T = 1.0f / (0.03f + 1e-8f);
        const float A = (gx + nx) * INV_T;
        const float R = (gr + nr) * INV_T;
        out[pix] = 1.0f / (1.0f + expf(R - A));
    }
}

extern "C" void kernel_launch(void* const* d_in, const int* in_sizes, int n_in,
                              void* d_out, int out_size, void* d_ws, size_t ws_size,
                              hipStream_t stream)
{
    const float* x       = (const float*)d_in[0];
    const float* qk_w    = (const float*)d_in[1];
    const float* qk_b    = (const float*)d_in[2];
    const float* score_w = (const float*)d_in[3];
    const float* score_b = (const float*)d_in[4];
    const float* noise_x = (const float*)d_in[5];
    const float* noise_r = (const float*)d_in[6];
    float* out = (float*)d_out;

    float* psum = (float*)d_ws;                    // 64*76*64  = 311296 floats
    float* G    = psum + (size_t)BB * NREG * 64;   // 64*128*64 = 524288 floats
    float* cc   = G + (size_t)BB * 128 * 64;       // 64*128    = 8192 floats
    // total 3.375 MB (same footprint as the previously-passing round)

    hipMemsetAsync(psum, 0, (size_t)BB * NREG * 64 * sizeof(float), stream);
    ka_pool<<<BB * HH, 256, 0, stream>>>(x, psum);
    kb_cells<<<BB * 4, 256, 0, stream>>>(qk_w, qk_b, score_w, score_b, psum, G, cc);
    kc_mask<<<BB * HH, 256, 0, stream>>>(x, G, cc, noise_x, noise_r, out);
}